// Round 2
// baseline (471.122 us; speedup 1.0000x reference)
//
#include <hip/hip_runtime.h>

// Problem constants (from reference): NU=NI=50000, DF=128, DL=64, E=1.2e6
constexpr int kNU = 50000;
constexpr int kDF = 128;
constexpr int kDL = 64;

// ---------------------------------------------------------------------------
// Kernel 1: per-row fused  [MLP (rows >= NU) | preference (rows < NU)]
//           -> L2 normalize -> @ W_conv -> xw   (one wave per row)
// ---------------------------------------------------------------------------
__global__ __launch_bounds__(256) void xw_kernel(
    const float* __restrict__ features,    // [NI, 128]
    const float* __restrict__ preference,  // [NU, 64]
    const float* __restrict__ W_mlp,       // [64, 128] row-major
    const float* __restrict__ b_mlp,       // [64]
    const float* __restrict__ W_conv,      // [64, 64] row-major
    float* __restrict__ xw,                // [N, 64]
    int n_total)
{
    // Wt[k*65 + l] = W_mlp[l][k]  (pad 65 -> conflict-free lane reads)
    __shared__ float Wt[kDF * 65];
    __shared__ float Wc[kDL * kDL];        // row-major as-is: lanes read consecutive c
    __shared__ float bs[kDL];
    __shared__ float frow[4][kDF];         // per-wave feature row
    __shared__ float xls[4][kDL];          // per-wave normalized row

    const int tid = threadIdx.x;
    for (int idx = tid; idx < kDL * kDF; idx += 256) {
        int k = idx & (kDF - 1);
        int l = idx >> 7;                  // idx = l*128 + k
        Wt[k * 65 + l] = W_mlp[idx];
    }
    for (int idx = tid; idx < kDL * kDL; idx += 256) Wc[idx] = W_conv[idx];
    if (tid < kDL) bs[tid] = b_mlp[tid];
    __syncthreads();

    const int lane   = tid & 63;
    const int wid    = tid >> 6;
    const int wglob  = blockIdx.x * 4 + wid;
    const int nwaves = gridDim.x * 4;

    for (int r = wglob; r < n_total; r += nwaves) {
        float v;
        if (r < kNU) {
            v = preference[(size_t)r * kDL + lane];
        } else {
            const float* fp = features + (size_t)(r - kNU) * kDF;
            frow[wid][lane]      = fp[lane];
            frow[wid][lane + 64] = fp[lane + 64];
            v = bs[lane];
            #pragma unroll 16
            for (int k = 0; k < kDF; ++k)
                v = fmaf(frow[wid][k], Wt[k * 65 + lane], v);   // broadcast * conflict-free
        }
        // L2 norm across the wave (row lives one element per lane)
        float ss = v * v;
        #pragma unroll
        for (int off = 32; off > 0; off >>= 1)
            ss += __shfl_xor(ss, off);
        const float xl = v / fmaxf(sqrtf(ss), 1e-12f);

        // conv: xw[r][lane] = sum_l xl[l] * W_conv[l][lane]
        xls[wid][lane] = xl;
        float acc = 0.f;
        #pragma unroll 16
        for (int l = 0; l < kDL; ++l)
            acc = fmaf(xls[wid][l], Wc[l * kDL + lane], acc);   // broadcast * conflict-free
        xw[(size_t)r * kDL + lane] = acc;
    }
}

// ---------------------------------------------------------------------------
// Kernel 2: edge scatter-add. One wave per edge, lane = channel.
// ---------------------------------------------------------------------------
__global__ __launch_bounds__(256) void scatter_kernel(
    const float* __restrict__ xw,
    const int* __restrict__ edge_index,    // [2, E] flat: src then dst
    float* __restrict__ out,
    int nE)
{
    const int lane = threadIdx.x & 63;
    const int e    = blockIdx.x * 4 + (threadIdx.x >> 6);
    if (e >= nE) return;
    const int s = edge_index[e];
    const int d = edge_index[nE + e];
    atomicAdd(out + (size_t)d * kDL + lane, xw[(size_t)s * kDL + lane]);
}

// ---------------------------------------------------------------------------
// Kernel 3: in-place leaky_relu (slope 0.01), float4-vectorized
// ---------------------------------------------------------------------------
__global__ __launch_bounds__(256) void leaky_kernel(float4* __restrict__ out, int n4)
{
    const int i = blockIdx.x * 256 + threadIdx.x;
    if (i >= n4) return;
    float4 v = out[i];
    v.x = v.x >= 0.f ? v.x : 0.01f * v.x;
    v.y = v.y >= 0.f ? v.y : 0.01f * v.y;
    v.z = v.z >= 0.f ? v.z : 0.01f * v.z;
    v.w = v.w >= 0.f ? v.w : 0.01f * v.w;
    out[i] = v;
}

extern "C" void kernel_launch(void* const* d_in, const int* in_sizes, int n_in,
                              void* d_out, int out_size, void* d_ws, size_t ws_size,
                              hipStream_t stream) {
    // inputs: 0=id_embedding (UNUSED by reference), 1=features, 2=preference,
    //         3=W_mlp, 4=b_mlp, 5=W_conv, 6=edge_index
    const float* features   = (const float*)d_in[1];
    const float* preference = (const float*)d_in[2];
    const float* W_mlp      = (const float*)d_in[3];
    const float* b_mlp      = (const float*)d_in[4];
    const float* W_conv     = (const float*)d_in[5];
    const int*   edge_index = (const int*)d_in[6];

    const int nE      = in_sizes[6] / 2;       // 1,200,000
    const int n_total = out_size / kDL;        // 100,000
    float* out = (float*)d_out;
    float* xw  = (float*)d_ws;                 // 25.6 MB scratch

    // d_out is re-poisoned before every timed launch -> must zero it ourselves.
    hipMemsetAsync(d_out, 0, (size_t)out_size * sizeof(float), stream);

    xw_kernel<<<512, 256, 0, stream>>>(features, preference, W_mlp, b_mlp,
                                       W_conv, xw, n_total);

    const int sgrid = (nE + 3) / 4;            // one wave per edge
    scatter_kernel<<<sgrid, 256, 0, stream>>>(xw, edge_index, out, nE);

    const int n4 = out_size / 4;
    leaky_kernel<<<(n4 + 255) / 256, 256, 0, stream>>>((float4*)d_out, n4);
}

// Round 7
// 416.591 us; speedup vs baseline: 1.1309x; 1.1309x over previous
//
#include <hip/hip_runtime.h>

// Problem constants (from reference): NU=NI=50000, DF=128, DL=64, E=1.2e6
constexpr int kNU = 50000;
constexpr int kDF = 128;
constexpr int kDL = 64;
constexpr int kXWBlocks = 2048;   // blocks of prep_kernel doing the xw transform

// ---------------------------------------------------------------------------
// prep_kernel: fused [xw transform | dst histogram] on disjoint block ranges.
//   xw part: 2 rows per wave; W_mlp^T + W_conv staged in LDS (shared across
//   both rows); feature operand read via wave-uniform scalar loads
//   (readfirstlane'd row index -> s_load), no frow LDS staging.
// ---------------------------------------------------------------------------
__global__ __launch_bounds__(256) void prep_kernel(
    const float* __restrict__ features,    // [NI, 128]
    const float* __restrict__ preference,  // [NU, 64]
    const float* __restrict__ W_mlp,       // [64, 128] row-major
    const float* __restrict__ b_mlp,       // [64]
    const float* __restrict__ W_conv,      // [64, 64] row-major
    const int* __restrict__ dst,           // edge_index + nE
    int* __restrict__ deg,                 // [n_total], pre-zeroed
    float* __restrict__ xw,                // [n_total, 64]
    int n_total, int nE)
{
    __shared__ float Wt[kDF * kDL];        // Wt[k*64+l] = W_mlp[l][k]
    __shared__ float Wc[kDL * kDL];        // row-major
    __shared__ float bs[kDL];
    __shared__ float xls[4][2][kDL];       // per-wave normalized row pair

    if (blockIdx.x >= kXWBlocks) {
        // ---- histogram path: 4 edges per thread ----
        const int b = blockIdx.x - kXWBlocks;
        int i = (b * 256 + threadIdx.x) * 4;
        if (i + 3 < nE) {
            const int4 d4 = *reinterpret_cast<const int4*>(dst + i);
            atomicAdd(&deg[d4.x], 1);
            atomicAdd(&deg[d4.y], 1);
            atomicAdd(&deg[d4.z], 1);
            atomicAdd(&deg[d4.w], 1);
        } else {
            for (; i < nE; ++i) atomicAdd(&deg[dst[i]], 1);
        }
        return;
    }

    // ---- xw path ----
    const int tid = threadIdx.x;
    for (int idx = tid; idx < kDL * kDF; idx += 256) {
        int k = idx & (kDF - 1);
        int l = idx >> 7;                  // idx = l*128 + k
        Wt[k * kDL + l] = W_mlp[idx];
    }
    for (int idx = tid; idx < kDL * kDL; idx += 256) Wc[idx] = W_conv[idx];
    if (tid < kDL) bs[tid] = b_mlp[tid];
    __syncthreads();

    const int lane   = tid & 63;
    const int wid    = tid >> 6;
    const int wglob  = blockIdx.x * 4 + wid;
    const int nwaves = kXWBlocks * 4;
    const int npairs = n_total >> 1;       // kNU even -> pairs never mix paths

    for (int pr = wglob; pr < npairs; pr += nwaves) {
        const int rA = 2 * pr, rB = rA + 1;
        float vA, vB;
        if (rA < kNU) {
            vA = preference[(size_t)rA * kDL + lane];
            vB = preference[(size_t)rB * kDL + lane];
        } else {
            const int iA = __builtin_amdgcn_readfirstlane(rA - kNU);
            const float* fA = features + (size_t)iA * kDF;   // uniform -> s_load
            const float* fB = fA + kDF;
            float a0 = bs[lane], a1 = 0.f, a2 = 0.f, a3 = 0.f;
            float c0 = bs[lane], c1 = 0.f, c2 = 0.f, c3 = 0.f;
            #pragma unroll 8
            for (int k = 0; k < kDF; k += 4) {
                const float w0 = Wt[(k)     * kDL + lane];
                const float w1 = Wt[(k + 1) * kDL + lane];
                const float w2 = Wt[(k + 2) * kDL + lane];
                const float w3 = Wt[(k + 3) * kDL + lane];
                a0 = fmaf(fA[k],     w0, a0);  c0 = fmaf(fB[k],     w0, c0);
                a1 = fmaf(fA[k + 1], w1, a1);  c1 = fmaf(fB[k + 1], w1, c1);
                a2 = fmaf(fA[k + 2], w2, a2);  c2 = fmaf(fB[k + 2], w2, c2);
                a3 = fmaf(fA[k + 3], w3, a3);  c3 = fmaf(fB[k + 3], w3, c3);
            }
            vA = (a0 + a1) + (a2 + a3);
            vB = (c0 + c1) + (c2 + c3);
        }
        // L2 norms across the wave (one element per lane)
        float sA = vA * vA, sB = vB * vB;
        #pragma unroll
        for (int o = 32; o > 0; o >>= 1) {
            sA += __shfl_xor(sA, o);
            sB += __shfl_xor(sB, o);
        }
        const float xlA = vA / fmaxf(sqrtf(sA), 1e-12f);
        const float xlB = vB / fmaxf(sqrtf(sB), 1e-12f);
        xls[wid][0][lane] = xlA;
        xls[wid][1][lane] = xlB;           // wave-private; same-wave LDS RAW is ordered

        float pA0 = 0.f, pA1 = 0.f, pB0 = 0.f, pB1 = 0.f;
        #pragma unroll 8
        for (int l = 0; l < kDL; l += 2) {
            const float w0  = Wc[(l)     * kDL + lane];
            const float w1  = Wc[(l + 1) * kDL + lane];
            const float xA0 = xls[wid][0][l], xA1 = xls[wid][0][l + 1];
            const float xB0 = xls[wid][1][l], xB1 = xls[wid][1][l + 1];
            pA0 = fmaf(xA0, w0, pA0);  pA1 = fmaf(xA1, w1, pA1);
            pB0 = fmaf(xB0, w0, pB0);  pB1 = fmaf(xB1, w1, pB1);
        }
        xw[(size_t)rA * kDL + lane] = pA0 + pA1;
        xw[(size_t)rB * kDL + lane] = pB0 + pB1;
    }
}

// ---------------------------------------------------------------------------
// single-block exclusive scan; 1024 threads x 8 elems per iter chunk (8192)
// ---------------------------------------------------------------------------
__global__ __launch_bounds__(1024) void scan_kernel(
    const int* __restrict__ deg, int* __restrict__ off, int n)
{
    __shared__ int wsum[16];
    __shared__ int running_s;
    const int tid  = threadIdx.x;
    const int lane = tid & 63;
    const int w    = tid >> 6;
    if (tid == 0) running_s = 0;
    __syncthreads();

    for (int base = 0; base < n; base += 8192) {
        const int i0 = base + tid * 8;
        int v[8];
        if (i0 + 7 < n) {
            const int4 u0 = *reinterpret_cast<const int4*>(deg + i0);
            const int4 u1 = *reinterpret_cast<const int4*>(deg + i0 + 4);
            v[0] = u0.x; v[1] = u0.y; v[2] = u0.z; v[3] = u0.w;
            v[4] = u1.x; v[5] = u1.y; v[6] = u1.z; v[7] = u1.w;
        } else {
            #pragma unroll
            for (int j = 0; j < 8; ++j) v[j] = (i0 + j < n) ? deg[i0 + j] : 0;
        }
        int t = 0;
        #pragma unroll
        for (int j = 0; j < 8; ++j) t += v[j];
        // inclusive wave scan of t
        int s = t;
        #pragma unroll
        for (int d = 1; d < 64; d <<= 1) {
            int u = __shfl_up(s, d);
            if (lane >= d) s += u;
        }
        if (lane == 63) wsum[w] = s;
        __syncthreads();
        if (w == 0 && lane < 16) {
            int ws_ = wsum[lane];
            #pragma unroll
            for (int d = 1; d < 16; d <<= 1) {
                int u = __shfl_up(ws_, d);
                if (lane >= d) ws_ += u;
            }
            wsum[lane] = ws_;
        }
        __syncthreads();
        int acc = running_s + (w ? wsum[w - 1] : 0) + (s - t);
        #pragma unroll
        for (int j = 0; j < 8; ++j) {
            if (i0 + j < n) off[i0 + j] = acc;
            acc += v[j];
        }
        __syncthreads();                   // all reads of running_s/wsum done
        if (tid == 0) running_s += wsum[15];
        __syncthreads();
    }
    if (tid == 0) off[n] = running_s;
}

// ---------------------------------------------------------------------------
// fill: csr[atomicAdd(&off[d],1)] = s.  Post-fill, off[r] = END of row r,
// so gather uses e0 = (r ? off[r-1] : 0), e1 = off[r].  4 edges/thread.
// ---------------------------------------------------------------------------
__global__ __launch_bounds__(256) void fill_kernel(
    const int* __restrict__ edge_index, int* __restrict__ off,
    int* __restrict__ csr_src, int nE)
{
    int i = (blockIdx.x * 256 + threadIdx.x) * 4;
    if (i + 3 < nE) {
        const int4 s4 = *reinterpret_cast<const int4*>(edge_index + i);
        const int4 d4 = *reinterpret_cast<const int4*>(edge_index + nE + i);
        int p;
        p = atomicAdd(&off[d4.x], 1); csr_src[p] = s4.x;
        p = atomicAdd(&off[d4.y], 1); csr_src[p] = s4.y;
        p = atomicAdd(&off[d4.z], 1); csr_src[p] = s4.z;
        p = atomicAdd(&off[d4.w], 1); csr_src[p] = s4.w;
    } else {
        for (; i < nE; ++i) {
            const int p = atomicAdd(&off[edge_index[nE + i]], 1);
            csr_src[p] = edge_index[i];
        }
    }
}

// ---------------------------------------------------------------------------
// gather: wave = 4 groups x 16 lanes; each group loads one edge row as
// float4 (16 B/lane); 8 edges in flight; cross-group shfl reduce; fused leaky.
// ---------------------------------------------------------------------------
__global__ __launch_bounds__(256) void gather_kernel(
    const float4* __restrict__ xw4,        // [n*16]
    const int* __restrict__ off,           // post-fill: end offsets
    const int* __restrict__ csr_src,
    float4* __restrict__ out4, int n)
{
    const int r = blockIdx.x * 4 + (threadIdx.x >> 6);
    if (r >= n) return;
    const int lane = threadIdx.x & 63;
    const int g = lane >> 4;               // edge slot within batch
    const int c = lane & 15;               // float4 column within row
    const int e0 = r ? off[r - 1] : 0;
    const int e1 = off[r];

    float4 acc = make_float4(0.f, 0.f, 0.f, 0.f);
    int e = e0;
    for (; e + 8 <= e1; e += 8) {
        const int s0 = csr_src[e + g];
        const int s1 = csr_src[e + 4 + g];
        const float4 v0 = xw4[(size_t)s0 * 16 + c];
        const float4 v1 = xw4[(size_t)s1 * 16 + c];
        acc.x += v0.x + v1.x;
        acc.y += v0.y + v1.y;
        acc.z += v0.z + v1.z;
        acc.w += v0.w + v1.w;
    }
    for (; e < e1; e += 4) {
        const int idx = e + g;
        if (idx < e1) {
            const int s = csr_src[idx];
            const float4 v = xw4[(size_t)s * 16 + c];
            acc.x += v.x; acc.y += v.y; acc.z += v.z; acc.w += v.w;
        }
    }
    // reduce across the 4 groups (lane strides 16, 32)
    acc.x += __shfl_xor(acc.x, 16);  acc.y += __shfl_xor(acc.y, 16);
    acc.z += __shfl_xor(acc.z, 16);  acc.w += __shfl_xor(acc.w, 16);
    acc.x += __shfl_xor(acc.x, 32);  acc.y += __shfl_xor(acc.y, 32);
    acc.z += __shfl_xor(acc.z, 32);  acc.w += __shfl_xor(acc.w, 32);

    if (lane < 16) {
        float4 o = acc;
        o.x = o.x >= 0.f ? o.x : 0.01f * o.x;
        o.y = o.y >= 0.f ? o.y : 0.01f * o.y;
        o.z = o.z >= 0.f ? o.z : 0.01f * o.z;
        o.w = o.w >= 0.f ? o.w : 0.01f * o.w;
        out4[(size_t)r * 16 + lane] = o;
    }
}

extern "C" void kernel_launch(void* const* d_in, const int* in_sizes, int n_in,
                              void* d_out, int out_size, void* d_ws, size_t ws_size,
                              hipStream_t stream) {
    // inputs: 0=id_embedding (UNUSED), 1=features, 2=preference,
    //         3=W_mlp, 4=b_mlp, 5=W_conv, 6=edge_index
    const float* features   = (const float*)d_in[1];
    const float* preference = (const float*)d_in[2];
    const float* W_mlp      = (const float*)d_in[3];
    const float* b_mlp      = (const float*)d_in[4];
    const float* W_conv     = (const float*)d_in[5];
    const int*   edge_index = (const int*)d_in[6];

    const int nE      = in_sizes[6] / 2;       // 1,200,000
    const int n_total = out_size / kDL;        // 100,000

    // ws layout (16B-aligned segments):
    //   xw  : n_total*64 f32   = 25,600,000 B
    //   off : (n_total+4) int  =    400,016 B
    //   deg : n_total int      =    400,000 B
    //   csr : nE int           =  4,800,000 B      total ~31.2 MB
    char* wp = (char*)d_ws;
    float* xw  = (float*)wp;   wp += (size_t)n_total * kDL * 4;
    int*   off = (int*)wp;     wp += (size_t)(n_total + 4) * 4;
    int*   deg = (int*)wp;     wp += (size_t)n_total * 4;
    int*   csr = (int*)wp;

    // deg must be zero before histogram (ws re-poisoned 0xAA each call)
    hipMemsetAsync(deg, 0, (size_t)n_total * 4, stream);

    const int egrid = (nE / 4 + 255) / 256;    // 4 edges/thread
    prep_kernel<<<kXWBlocks + egrid, 256, 0, stream>>>(
        features, preference, W_mlp, b_mlp, W_conv,
        edge_index + nE, deg, xw, n_total, nE);

    scan_kernel<<<1, 1024, 0, stream>>>(deg, off, n_total);
    fill_kernel<<<egrid, 256, 0, stream>>>(edge_index, off, csr, nE);

    gather_kernel<<<(n_total + 3) / 4, 256, 0, stream>>>(
        (const float4*)xw, off, csr, (float4*)d_out, n_total);
}

// Round 8
// 348.518 us; speedup vs baseline: 1.3518x; 1.1953x over previous
//
#include <hip/hip_runtime.h>
#include <hip/hip_bf16.h>

// Problem constants (from reference): NU=NI=50000, DF=128, DL=64, E=1.2e6
constexpr int kNU = 50000;
constexpr int kDF = 128;
constexpr int kDL = 64;

__device__ __forceinline__ float bf16hi_to_f(unsigned int u) {
    return __uint_as_float(u);
}

// ---------------------------------------------------------------------------
// xw_kernel: [MLP (rows >= NU) | preference] -> L2 normalize -> @W_conv
//            -> bf16 xw table.  2 rows per wave share the Wt/Wc LDS reads;
//            frow/xls broadcast via float4 ds_read_b128; Wt padded *65
//            (65 = 1 mod 32 -> conflict-free staging AND reads).
// ---------------------------------------------------------------------------
__global__ __launch_bounds__(256) void xw_kernel(
    const float* __restrict__ features,    // [NI, 128]
    const float* __restrict__ preference,  // [NU, 64]
    const float* __restrict__ W_mlp,       // [64, 128] row-major
    const float* __restrict__ b_mlp,       // [64]
    const float* __restrict__ W_conv,      // [64, 64] row-major
    __hip_bfloat16* __restrict__ xwb,      // [n, 64] bf16
    int n_total)
{
    __shared__ float Wt[kDF * 65];         // Wt[k*65+l] = W_mlp[l][k]
    __shared__ float Wc[kDL * kDL];        // row-major as-is
    __shared__ float bs[kDL];
    __shared__ float frow[4][2][kDF];      // per-wave feature rows (pair)
    __shared__ float xls[4][2][kDL];       // per-wave normalized rows (pair)

    const int tid = threadIdx.x;
    for (int idx = tid; idx < kDL * kDF; idx += 256) {
        int k = idx & (kDF - 1);
        int l = idx >> 7;                  // idx = l*128 + k
        Wt[k * 65 + l] = W_mlp[idx];       // banks stride 1 in k -> conflict-free
    }
    for (int idx = tid; idx < kDL * kDL; idx += 256) Wc[idx] = W_conv[idx];
    if (tid < kDL) bs[tid] = b_mlp[tid];
    __syncthreads();

    const int lane   = tid & 63;
    const int wid    = tid >> 6;
    const int wglob  = blockIdx.x * 4 + wid;
    const int nwaves = gridDim.x * 4;
    const int npairs = n_total >> 1;       // NU even -> a pair never mixes paths

    for (int pr = wglob; pr < npairs; pr += nwaves) {
        const int rA = 2 * pr, rB = rA + 1;
        float vA, vB;
        if (rA < kNU) {
            vA = preference[(size_t)rA * kDL + lane];
            vB = preference[(size_t)rB * kDL + lane];
        } else {
            const float* fA = features + (size_t)(rA - kNU) * kDF;
            const float* fB = fA + kDF;
            frow[wid][0][lane]      = fA[lane];
            frow[wid][0][lane + 64] = fA[lane + 64];
            frow[wid][1][lane]      = fB[lane];
            frow[wid][1][lane + 64] = fB[lane + 64];
            float a0 = bs[lane], a1 = 0.f, a2 = 0.f, a3 = 0.f;
            float c0 = bs[lane], c1 = 0.f, c2 = 0.f, c3 = 0.f;
            #pragma unroll
            for (int k = 0; k < kDF; k += 4) {
                const float4 fa = *reinterpret_cast<const float4*>(&frow[wid][0][k]);
                const float4 fb = *reinterpret_cast<const float4*>(&frow[wid][1][k]);
                const float w0 = Wt[(k)     * 65 + lane];
                const float w1 = Wt[(k + 1) * 65 + lane];
                const float w2 = Wt[(k + 2) * 65 + lane];
                const float w3 = Wt[(k + 3) * 65 + lane];
                a0 = fmaf(fa.x, w0, a0);  c0 = fmaf(fb.x, w0, c0);
                a1 = fmaf(fa.y, w1, a1);  c1 = fmaf(fb.y, w1, c1);
                a2 = fmaf(fa.z, w2, a2);  c2 = fmaf(fb.z, w2, c2);
                a3 = fmaf(fa.w, w3, a3);  c3 = fmaf(fb.w, w3, c3);
            }
            vA = (a0 + a1) + (a2 + a3);
            vB = (c0 + c1) + (c2 + c3);
        }
        // L2 norms across the wave
        float sA = vA * vA, sB = vB * vB;
        #pragma unroll
        for (int o = 32; o > 0; o >>= 1) {
            sA += __shfl_xor(sA, o);
            sB += __shfl_xor(sB, o);
        }
        const float xlA = vA / fmaxf(sqrtf(sA), 1e-12f);
        const float xlB = vB / fmaxf(sqrtf(sB), 1e-12f);
        xls[wid][0][lane] = xlA;
        xls[wid][1][lane] = xlB;

        float pA0 = 0.f, pA1 = 0.f, pA2 = 0.f, pA3 = 0.f;
        float pB0 = 0.f, pB1 = 0.f, pB2 = 0.f, pB3 = 0.f;
        #pragma unroll
        for (int l = 0; l < kDL; l += 4) {
            const float4 xA = *reinterpret_cast<const float4*>(&xls[wid][0][l]);
            const float4 xB = *reinterpret_cast<const float4*>(&xls[wid][1][l]);
            const float w0 = Wc[(l)     * kDL + lane];
            const float w1 = Wc[(l + 1) * kDL + lane];
            const float w2 = Wc[(l + 2) * kDL + lane];
            const float w3 = Wc[(l + 3) * kDL + lane];
            pA0 = fmaf(xA.x, w0, pA0);  pB0 = fmaf(xB.x, w0, pB0);
            pA1 = fmaf(xA.y, w1, pA1);  pB1 = fmaf(xB.y, w1, pB1);
            pA2 = fmaf(xA.z, w2, pA2);  pB2 = fmaf(xB.z, w2, pB2);
            pA3 = fmaf(xA.w, w3, pA3);  pB3 = fmaf(xB.w, w3, pB3);
        }
        xwb[(size_t)rA * kDL + lane] = __float2bfloat16((pA0 + pA1) + (pA2 + pA3));
        xwb[(size_t)rB * kDL + lane] = __float2bfloat16((pB0 + pB1) + (pB2 + pB3));
    }
}

// ---------------------------------------------------------------------------
// hist: dst-degree histogram, 4 edges/thread, no LDS.
// ---------------------------------------------------------------------------
__global__ __launch_bounds__(256) void hist_kernel(
    const int* __restrict__ dst, int* __restrict__ deg, int nE)
{
    int i = (blockIdx.x * 256 + threadIdx.x) * 4;
    if (i + 3 < nE) {
        const int4 d4 = *reinterpret_cast<const int4*>(dst + i);
        atomicAdd(&deg[d4.x], 1);
        atomicAdd(&deg[d4.y], 1);
        atomicAdd(&deg[d4.z], 1);
        atomicAdd(&deg[d4.w], 1);
    } else {
        for (; i < nE; ++i) atomicAdd(&deg[dst[i]], 1);
    }
}

// ---------------------------------------------------------------------------
// scan_part: per-block (1024-elem) local exclusive scan -> off, block sum -> part
// ---------------------------------------------------------------------------
__global__ __launch_bounds__(256) void scan_part(
    const int* __restrict__ deg, int* __restrict__ off,
    int* __restrict__ part, int n)
{
    __shared__ int wsum[4];
    const int tid = threadIdx.x, lane = tid & 63, w = tid >> 6;
    const int i0 = (blockIdx.x * 256 + tid) * 4;
    int4 v = make_int4(0, 0, 0, 0);
    if (i0 + 3 < n) {
        v = *reinterpret_cast<const int4*>(deg + i0);
    } else {
        if (i0     < n) v.x = deg[i0];
        if (i0 + 1 < n) v.y = deg[i0 + 1];
        if (i0 + 2 < n) v.z = deg[i0 + 2];
    }
    const int t = v.x + v.y + v.z + v.w;
    int s = t;
    #pragma unroll
    for (int d = 1; d < 64; d <<= 1) {
        int u = __shfl_up(s, d);
        if (lane >= d) s += u;
    }
    if (lane == 63) wsum[w] = s;
    __syncthreads();
    int wexcl = 0;
    if (w > 0) wexcl += wsum[0];
    if (w > 1) wexcl += wsum[1];
    if (w > 2) wexcl += wsum[2];
    const int pfx = wexcl + (s - t);
    if (i0     < n) off[i0]     = pfx;
    if (i0 + 1 < n) off[i0 + 1] = pfx + v.x;
    if (i0 + 2 < n) off[i0 + 2] = pfx + v.x + v.y;
    if (i0 + 3 < n) off[i0 + 3] = pfx + v.x + v.y + v.z;
    if (tid == 0) part[blockIdx.x] = wsum[0] + wsum[1] + wsum[2] + wsum[3];
}

// ---------------------------------------------------------------------------
// scan_apply: block b adds prefix = sum(part[j<b]) to its off segment.
// nblk <= 128 so one wave reduces the whole part array (2 regs/lane).
// ---------------------------------------------------------------------------
__global__ __launch_bounds__(256) void scan_apply(
    const int* __restrict__ part, int* __restrict__ off, int n)
{
    const int b = blockIdx.x;
    if (b == 0) return;                    // prefix 0
    const int tid = threadIdx.x, lane = tid & 63;
    int pv = (lane < b) ? part[lane] : 0;
    if (lane + 64 < b) pv += part[lane + 64];
    #pragma unroll
    for (int o = 32; o > 0; o >>= 1) pv += __shfl_xor(pv, o);
    const int i0 = (b * 256 + tid) * 4;
    if (i0 + 3 < n) {
        int4 v = *reinterpret_cast<int4*>(off + i0);
        v.x += pv; v.y += pv; v.z += pv; v.w += pv;
        *reinterpret_cast<int4*>(off + i0) = v;
    } else {
        if (i0     < n) off[i0]     += pv;
        if (i0 + 1 < n) off[i0 + 1] += pv;
        if (i0 + 2 < n) off[i0 + 2] += pv;
    }
}

// ---------------------------------------------------------------------------
// fill: csr[atomicAdd(&off[d],1)] = s.  Post-fill off[r] = END of row r,
// so gather uses e0 = (r ? off[r-1] : 0), e1 = off[r].
// ---------------------------------------------------------------------------
__global__ __launch_bounds__(256) void fill_kernel(
    const int* __restrict__ edge_index, int* __restrict__ off,
    int* __restrict__ csr_src, int nE)
{
    int i = (blockIdx.x * 256 + threadIdx.x) * 4;
    if (i + 3 < nE) {
        const int4 s4 = *reinterpret_cast<const int4*>(edge_index + i);
        const int4 d4 = *reinterpret_cast<const int4*>(edge_index + nE + i);
        int p;
        p = atomicAdd(&off[d4.x], 1); csr_src[p] = s4.x;
        p = atomicAdd(&off[d4.y], 1); csr_src[p] = s4.y;
        p = atomicAdd(&off[d4.z], 1); csr_src[p] = s4.z;
        p = atomicAdd(&off[d4.w], 1); csr_src[p] = s4.w;
    } else {
        for (; i < nE; ++i) {
            const int p = atomicAdd(&off[edge_index[nE + i]], 1);
            csr_src[p] = edge_index[i];
        }
    }
}

// ---------------------------------------------------------------------------
// gather: one wave per dst row. 8 groups x 8 lanes; each group loads one
// edge's full 64-bf16 row (uint4 = 8 bf16 per lane). The whole CSR row is
// preloaded in one coalesced load (csr[e0+lane]) and redistributed by shfl,
// so the per-iteration chain is shfl -> load -> add (no csr latency).
// Cross-group shfl_xor reduce; fused leaky_relu; float4 stores.
// ---------------------------------------------------------------------------
__global__ __launch_bounds__(256) void gather_kernel(
    const uint4* __restrict__ xwb4,        // row r = 8 x uint4 (64 bf16)
    const int* __restrict__ off,           // post-fill: end offsets
    const int* __restrict__ csr,
    float4* __restrict__ out4, int n)
{
    const int r = blockIdx.x * 4 + (threadIdx.x >> 6);
    if (r >= n) return;
    const int lane = threadIdx.x & 63;
    const int g = lane >> 3;               // edge slot within batch of 8
    const int c = lane & 7;                // uint4 column within row
    const int e0  = r ? off[r - 1] : 0;
    const int deg = off[r] - e0;

    const int s_all = (lane < deg) ? csr[e0 + lane] : 0;

    float acc[8];
    #pragma unroll
    for (int j = 0; j < 8; ++j) acc[j] = 0.f;

    for (int base = 0; base < deg; base += 8) {
        const int idx = base + g;
        int s = (idx < 64) ? __shfl(s_all, idx)
                           : ((idx < deg) ? csr[e0 + idx] : 0);
        if (idx < deg) {
            const uint4 v = xwb4[(size_t)s * 8 + c];
            acc[0] += bf16hi_to_f(v.x << 16);
            acc[1] += bf16hi_to_f(v.x & 0xffff0000u);
            acc[2] += bf16hi_to_f(v.y << 16);
            acc[3] += bf16hi_to_f(v.y & 0xffff0000u);
            acc[4] += bf16hi_to_f(v.z << 16);
            acc[5] += bf16hi_to_f(v.z & 0xffff0000u);
            acc[6] += bf16hi_to_f(v.w << 16);
            acc[7] += bf16hi_to_f(v.w & 0xffff0000u);
        }
    }
    #pragma unroll
    for (int j = 0; j < 8; ++j) {
        acc[j] += __shfl_xor(acc[j], 8);
        acc[j] += __shfl_xor(acc[j], 16);
        acc[j] += __shfl_xor(acc[j], 32);
    }
    if (g == 0) {
        #pragma unroll
        for (int j = 0; j < 8; ++j)
            acc[j] = acc[j] >= 0.f ? acc[j] : 0.01f * acc[j];
        const float4 o0 = make_float4(acc[0], acc[1], acc[2], acc[3]);
        const float4 o1 = make_float4(acc[4], acc[5], acc[6], acc[7]);
        out4[(size_t)r * 16 + c * 2]     = o0;
        out4[(size_t)r * 16 + c * 2 + 1] = o1;
    }
}

extern "C" void kernel_launch(void* const* d_in, const int* in_sizes, int n_in,
                              void* d_out, int out_size, void* d_ws, size_t ws_size,
                              hipStream_t stream) {
    // inputs: 0=id_embedding (UNUSED), 1=features, 2=preference,
    //         3=W_mlp, 4=b_mlp, 5=W_conv, 6=edge_index
    const float* features   = (const float*)d_in[1];
    const float* preference = (const float*)d_in[2];
    const float* W_mlp      = (const float*)d_in[3];
    const float* b_mlp      = (const float*)d_in[4];
    const float* W_conv     = (const float*)d_in[5];
    const int*   edge_index = (const int*)d_in[6];

    const int nE      = in_sizes[6] / 2;       // 1,200,000
    const int n_total = out_size / kDL;        // 100,000

    // ws layout (16B-aligned segments):
    //   xwb  : n_total*64 bf16 = 12,800,000 B
    //   off  : (n_total+4) int =    400,016 B
    //   deg  : n_total int     =    400,000 B
    //   part : 128 int         =        512 B
    //   csr  : nE int          =  4,800,000 B      total ~18.4 MB
    char* wp = (char*)d_ws;
    __hip_bfloat16* xwb = (__hip_bfloat16*)wp;  wp += (size_t)n_total * kDL * 2;
    int* off  = (int*)wp;                        wp += (size_t)(n_total + 4) * 4;
    int* deg  = (int*)wp;                        wp += (size_t)n_total * 4;
    int* part = (int*)wp;                        wp += 512;
    int* csr  = (int*)wp;

    // deg must be zero before histogram (ws re-poisoned 0xAA each call)
    hipMemsetAsync(deg, 0, (size_t)n_total * 4, stream);

    xw_kernel<<<1024, 256, 0, stream>>>(features, preference, W_mlp, b_mlp,
                                        W_conv, xwb, n_total);

    const int egrid = (nE / 4 + 255) / 256;    // 4 edges/thread
    hist_kernel<<<egrid, 256, 0, stream>>>(edge_index + nE, deg, nE);

    const int nblk = (n_total + 1023) / 1024;  // 98 (must be <= 128)
    scan_part<<<nblk, 256, 0, stream>>>(deg, off, part, n_total);
    scan_apply<<<nblk, 256, 0, stream>>>(part, off, n_total);

    fill_kernel<<<egrid, 256, 0, stream>>>(edge_index, off, csr, nE);

    gather_kernel<<<(n_total + 3) / 4, 256, 0, stream>>>(
        (const uint4*)xwb, off, csr, (float4*)d_out, n_total);
}